// Round 5
// baseline (587.877 us; speedup 1.0000x reference)
//
#include <hip/hip_runtime.h>

typedef unsigned short u16;
typedef unsigned int   u32;
typedef __bf16 bf16x8 __attribute__((ext_vector_type(8)));
typedef float  f32x4  __attribute__((ext_vector_type(4)));

#define DD 1024

__device__ __forceinline__ u16 f2bf(float f) {
  u32 u = __float_as_uint(f);
  u32 r = (u + 0x7FFFu + ((u >> 16) & 1u)) >> 16;
  return (u16)r;
}

// ---------------------------------------------------------------------------
// k0: convert x fp32 -> xb bf16 (mode A only). 256 blocks x 256.
// ---------------------------------------------------------------------------
__global__ __launch_bounds__(256) void k0_convert(
    const float4* __restrict__ x4, ushort4* __restrict__ xb4) {
  const int t0 = blockIdx.x * 256 + threadIdx.x;          // 65536 threads
  for (long i = t0; i < 4194304; i += 65536) {            // 16.8M elems / 4
    float4 v = x4[i];
    ushort4 o;
    o.x = f2bf(v.x); o.y = f2bf(v.y); o.z = f2bf(v.z); o.w = f2bf(v.w);
    xb4[i] = o;
  }
}

// ---------------------------------------------------------------------------
// k1: blocks 0..63  : pooled col-sums of x (fp32 atomics)
//     blocks 64..95 : AWBW[16][1024] = {A,B}@W_base (fp32 atomics, split-i)
//     blocks 96..99 : Mbuf: 4 Gram 8x8 (A.Us, B.Us, A.Ul, B.Ul)
//     blocks 100..355: Wt[n][k] = bf16(W[k][n])  (transpose + convert)
// ---------------------------------------------------------------------------
__global__ __launch_bounds__(256) void k1_pre(
    const float* __restrict__ x, const float* __restrict__ W,
    const float* __restrict__ Ao, const float* __restrict__ Bo,
    const float* __restrict__ Us, const float* __restrict__ Ul,
    float* __restrict__ pooled, float* __restrict__ AWBW,
    float* __restrict__ Mbuf, u16* __restrict__ Wt) {
  const int bid = blockIdx.x, tid = threadIdx.x;
  if (bid < 64) {
    const int b = bid >> 4;
    const long r0 = (long)bid * 256;
    const int c0 = tid * 4;
    float s0 = 0.f, s1 = 0.f, s2 = 0.f, s3 = 0.f;
    for (int r = 0; r < 256; r++) {
      float4 v = *(const float4*)(x + (r0 + r) * DD + c0);
      s0 += v.x; s1 += v.y; s2 += v.z; s3 += v.w;
    }
    atomicAdd(&pooled[b * DD + c0 + 0], s0);
    atomicAdd(&pooled[b * DD + c0 + 1], s1);
    atomicAdd(&pooled[b * DD + c0 + 2], s2);
    atomicAdd(&pooled[b * DD + c0 + 3], s3);
  } else if (bid < 96) {
    __shared__ float red2[2][128][16];
    const int m = bid - 64;
    const int n = (m & 7) * 128 + (tid & 127), q = m >> 3, ih = tid >> 7;
    float acc[16];
#pragma unroll
    for (int k = 0; k < 16; k++) acc[k] = 0.f;
    const int ib = q * 256 + ih * 128;
    for (int i = ib; i < ib + 128; i++) {
      float wv = W[(long)i * DD + n];
#pragma unroll
      for (int k = 0; k < 8; k++) {
        acc[k]     += Ao[k * DD + i] * wv;
        acc[k + 8] += Bo[k * DD + i] * wv;
      }
    }
#pragma unroll
    for (int k = 0; k < 16; k++) red2[ih][tid & 127][k] = acc[k];
    __syncthreads();
    if (ih == 0)
#pragma unroll
      for (int k = 0; k < 16; k++)
        atomicAdd(&AWBW[k * DD + n], red2[0][tid][k] + red2[1][tid][k]);
  } else if (bid < 100) {
    __shared__ float red[64][4];
    const int m = bid - 96;
    const float* L  = (m == 0 || m == 2) ? Ao : Bo;
    const float* Rr = (m < 2) ? Us : Ul;
    const int o = tid >> 2, ch = tid & 3;
    const int k = o >> 3, kp = o & 7;
    float a = 0.f;
    for (int i = ch * 256; i < ch * 256 + 256; i++)
      a += L[(long)k * DD + i] * Rr[(long)kp * DD + i];
    red[o][ch] = a;
    __syncthreads();
    if (tid < 64) Mbuf[m * 64 + tid] = red[tid][0] + red[tid][1] + red[tid][2] + red[tid][3];
  } else {
    __shared__ u16 T[64][66];
    const int t = bid - 100, tr = t >> 4, tc = t & 15;
#pragma unroll
    for (int q2 = 0; q2 < 16; q2++) {
      int idx = q2 * 256 + tid, r = idx >> 6, c = idx & 63;
      T[r][c] = f2bf(W[(long)(tr * 64 + r) * DD + tc * 64 + c]);
    }
    __syncthreads();
#pragma unroll
    for (int q2 = 0; q2 < 16; q2++) {
      int idx = q2 * 256 + tid, c = idx >> 6, r = idx & 63;
      Wt[(long)(tc * 64 + c) * DD + tr * 64 + r] = T[r][c];
    }
  }
}

// ---------------------------------------------------------------------------
// k2: blocks 0..3: pooled mean -> LN -> MLP(tanh-gelu) -> gates[b][24]
//     blocks 4..7: pack RwT[n][32] = bf16{AW(8) BW(8) Vs(8) Vl(8)}(., n)
// ---------------------------------------------------------------------------
__global__ __launch_bounds__(256) void k2_gates_pack(
    const float* __restrict__ pooledsum, const float* __restrict__ AWBW,
    const float* Vs, const float* Vl,
    const float* lng, const float* lnb, const float* Wc1, const float* bc1,
    const float* Wc2, const float* bc2, const float* Wrg, const float* brg,
    const float* Wrc, const float* brc, const float* Wsg, const float* bsg,
    const float* Wlc, const float* blc,
    float* __restrict__ gates, u16* __restrict__ RwT) {
  const int tid = threadIdx.x;
  if (blockIdx.x < 4) {
    __shared__ float z[1024];
    __shared__ float red[256];
    __shared__ float g1[128], hb[128];
    const int b = blockIdx.x;
    float s = 0.f, sq = 0.f;
    for (int q = 0; q < 4; q++) {
      float v = pooledsum[b * DD + q * 256 + tid] * (1.f / 4096.f);
      z[q * 256 + tid] = v; s += v; sq += v * v;
    }
    red[tid] = s; __syncthreads();
    for (int st = 128; st > 0; st >>= 1) { if (tid < st) red[tid] += red[tid + st]; __syncthreads(); }
    float mu = red[0] * (1.f / 1024.f);
    __syncthreads();
    red[tid] = sq; __syncthreads();
    for (int st = 128; st > 0; st >>= 1) { if (tid < st) red[tid] += red[tid + st]; __syncthreads(); }
    float var = red[0] * (1.f / 1024.f) - mu * mu;
    float rs = rsqrtf(var + 1e-5f);
    __syncthreads();
    for (int q = 0; q < 4; q++) {
      int d = q * 256 + tid;
      z[d] = (z[d] - mu) * rs * lng[d] + lnb[d];
    }
    __syncthreads();
    {
      const int j = tid & 127, hf = tid >> 7;
      float a = 0.f;
      for (int d = hf * 512; d < hf * 512 + 512; d++) a += z[d] * Wc1[(long)d * 128 + j];
      red[tid] = a;
    }
    __syncthreads();
    if (tid < 128) {
      float hv = red[tid] + red[tid + 128] + bc1[tid];
      float th = tanhf(0.7978845608028654f * (hv + 0.044715f * hv * hv * hv));
      g1[tid] = 0.5f * hv * (1.f + th);
    }
    __syncthreads();
    if (tid < 128) {
      float a = bc2[tid];
      for (int i = 0; i < 128; i++) a += g1[i] * Wc2[(long)i * 128 + tid];
      hb[tid] = a;
    }
    __syncthreads();
    if (tid < 25) {
      const float* Wp; int stride, ci; float bias;
      if (tid == 0)      { Wp = Wrg; stride = 1; ci = 0;        bias = brg[0]; }
      else if (tid < 9)  { Wp = Wrc; stride = 8; ci = tid - 1;  bias = brc[tid - 1]; }
      else if (tid < 17) { Wp = Wsg; stride = 8; ci = tid - 9;  bias = bsg[tid - 9]; }
      else               { Wp = Wlc; stride = 8; ci = tid - 17; bias = blc[tid - 17]; }
      float a = bias;
      for (int i = 0; i < 128; i++) a += hb[i] * Wp[(long)i * stride + ci];
      red[tid] = (tid == 0) ? 1.f / (1.f + expf(-a)) : tanhf(a);
    }
    __syncthreads();
    if (tid < 24) {
      float g = red[0];
      gates[b * 32 + tid] = (tid < 8) ? g * red[1 + tid] : red[1 + tid];
    }
  } else {
    const int n = (int)(blockIdx.x - 4) * 256 + tid;
#pragma unroll
    for (int j = 0; j < 8; j++) {
      RwT[n * 32 + j]      = f2bf(AWBW[j * DD + n]);
      RwT[n * 32 + 8 + j]  = f2bf(AWBW[(8 + j) * DD + n]);
      RwT[n * 32 + 16 + j] = f2bf(Vs[(long)j * DD + n]);
      RwT[n * 32 + 24 + j] = f2bf(Vl[(long)j * DD + n]);
    }
  }
}

// ---------------------------------------------------------------------------
// k3: fused GEMM. kc=0..31: out-acc += x@W (128x128), proj-acc += x@P^T
//     (P=[Ao;Bo;Us;Ul]). Then in-block coefficients + final rank-32 K-chunk.
//     XB: A staged from pre-converted xb bf16; else from fp32 x w/ convert.
//     Output fp32.
// ---------------------------------------------------------------------------
template <bool XB>
__global__ __launch_bounds__(256) void k3_fused(
    const float* __restrict__ xf, const u16* __restrict__ xb,
    const u16* __restrict__ Wt,
    const float* __restrict__ Ao, const float* __restrict__ Bo,
    const float* __restrict__ Us, const float* __restrict__ Ul,
    const float* __restrict__ gates, const float* __restrict__ Mbuf,
    const u16* __restrict__ RwT, const float* __restrict__ bb,
    float* __restrict__ out) {
  __shared__ __align__(16) u16 At[4096];
  __shared__ __align__(16) u16 Bt[4096];
  __shared__ __align__(16) u16 Pt[1024];
  __shared__ float projF[128 * 32];
  __shared__ __align__(16) u16 wLds[4096];
  __shared__ float Ml[256];
  __shared__ float gl[24];
  const int tid = threadIdx.x, lane = tid & 63, w = tid >> 6;
  const int quad = lane >> 4, lrow = lane & 15;
  const int bn = blockIdx.x & 7, bm = blockIdx.x >> 3;
  const long m0 = (long)bm * 128;
  const int n0 = bn * 128;
  const int batch = bm >> 5;
  Ml[tid] = Mbuf[tid];
  if (tid < 24) gl[tid] = gates[batch * 32 + tid];
  const int mw = (w & 1) * 64, nw = (w >> 1) * 64;
  const int p0 = (w * 2) * 1024 + lane * 16, p1 = p0 + 1024;   // byte offsets
  // fp32-staging thread mapping: fi = i*256+tid -> row=fi>>3, col4=fi&7
  f32x4 acc[4][4] = {};
  f32x4 acc2[2][2] = {};
  for (int kc = 0; kc < 32; kc++) {
    // ---- A tile: 128 rows x 32 k (bf16) ----
    if (XB) {
      uint4 va0 = *(const uint4*)((const char*)xb + (m0 + (p0 >> 6)) * 2048 + kc * 64 + (p0 & 63));
      uint4 va1 = *(const uint4*)((const char*)xb + (m0 + (p1 >> 6)) * 2048 + kc * 64 + (p1 & 63));
      uint4 vb0 = *(const uint4*)((const char*)Wt + (long)(n0 + (p0 >> 6)) * 2048 + kc * 64 + (p0 & 63));
      uint4 vb1 = *(const uint4*)((const char*)Wt + (long)(n0 + (p1 >> 6)) * 2048 + kc * 64 + (p1 & 63));
      uint4 vp;
      if (tid < 128) {
        int prow = tid >> 2, pc = (tid & 3) * 8;               // 8 fp32 -> need 2 float4
        const float* Pr = prow < 8  ? Ao + prow * DD
                        : prow < 16 ? Bo + (prow - 8) * DD
                        : prow < 24 ? Us + (prow - 16) * DD
                                    : Ul + (prow - 24) * DD;
        float4 f0 = *(const float4*)(Pr + kc * 32 + pc);
        float4 f1 = *(const float4*)(Pr + kc * 32 + pc + 4);
        ushort4 o0, o1;
        o0.x = f2bf(f0.x); o0.y = f2bf(f0.y); o0.z = f2bf(f0.z); o0.w = f2bf(f0.w);
        o1.x = f2bf(f1.x); o1.y = f2bf(f1.y); o1.z = f2bf(f1.z); o1.w = f2bf(f1.w);
        vp.x = (u32)o0.x | ((u32)o0.y << 16); vp.y = (u32)o0.z | ((u32)o0.w << 16);
        vp.z = (u32)o1.x | ((u32)o1.y << 16); vp.w = (u32)o1.z | ((u32)o1.w << 16);
      }
      *(uint4*)((char*)At + p0) = va0;
      *(uint4*)((char*)At + p1) = va1;
      *(uint4*)((char*)Bt + p0) = vb0;
      *(uint4*)((char*)Bt + p1) = vb1;
      if (tid < 128) *(uint4*)((char*)Pt + (tid >> 2) * 64 + (tid & 3) * 16) = vp;
    } else {
      ushort4 oa[4];
#pragma unroll
      for (int i = 0; i < 4; i++) {
        int fi = i * 256 + tid, row = fi >> 3, c4 = (fi & 7) * 4;
        float4 v = *(const float4*)(xf + (m0 + row) * DD + kc * 32 + c4);
        oa[i].x = f2bf(v.x); oa[i].y = f2bf(v.y); oa[i].z = f2bf(v.z); oa[i].w = f2bf(v.w);
      }
      uint4 vb0 = *(const uint4*)((const char*)Wt + (long)(n0 + (p0 >> 6)) * 2048 + kc * 64 + (p0 & 63));
      uint4 vb1 = *(const uint4*)((const char*)Wt + (long)(n0 + (p1 >> 6)) * 2048 + kc * 64 + (p1 & 63));
#pragma unroll
      for (int i = 0; i < 4; i++) {
        int fi = i * 256 + tid, row = fi >> 3, c4 = (fi & 7) * 4;
        *(ushort4*)(At + row * 32 + c4) = oa[i];
      }
      *(uint4*)((char*)Bt + p0) = vb0;
      *(uint4*)((char*)Bt + p1) = vb1;
      if (tid < 128) {
        int prow = tid >> 2, pc = (tid & 3) * 8;
        const float* Pr = prow < 8  ? Ao + prow * DD
                        : prow < 16 ? Bo + (prow - 8) * DD
                        : prow < 24 ? Us + (prow - 16) * DD
                                    : Ul + (prow - 24) * DD;
        float4 f0 = *(const float4*)(Pr + kc * 32 + pc);
        float4 f1 = *(const float4*)(Pr + kc * 32 + pc + 4);
        ushort4 o0, o1;
        o0.x = f2bf(f0.x); o0.y = f2bf(f0.y); o0.z = f2bf(f0.z); o0.w = f2bf(f0.w);
        o1.x = f2bf(f1.x); o1.y = f2bf(f1.y); o1.z = f2bf(f1.z); o1.w = f2bf(f1.w);
        *(ushort4*)(Pt + prow * 32 + pc) = o0;
        *(ushort4*)(Pt + prow * 32 + pc + 4) = o1;
      }
    }
    __syncthreads();
    bf16x8 af[4], bq[4], af2[2], bp[2];
#pragma unroll
    for (int tm = 0; tm < 4; tm++)
      af[tm] = *(const bf16x8*)(At + (mw + tm * 16 + lrow) * 32 + quad * 8);
#pragma unroll
    for (int tn = 0; tn < 4; tn++)
      bq[tn] = *(const bf16x8*)(Bt + (nw + tn * 16 + lrow) * 32 + quad * 8);
#pragma unroll
    for (int t2 = 0; t2 < 2; t2++)
      af2[t2] = *(const bf16x8*)(At + (w * 32 + t2 * 16 + lrow) * 32 + quad * 8);
#pragma unroll
    for (int tn2 = 0; tn2 < 2; tn2++)
      bp[tn2] = *(const bf16x8*)(Pt + (tn2 * 16 + lrow) * 32 + quad * 8);
#pragma unroll
    for (int tm = 0; tm < 4; tm++)
#pragma unroll
      for (int tn = 0; tn < 4; tn++)
        acc[tm][tn] = __builtin_amdgcn_mfma_f32_16x16x32_bf16(af[tm], bq[tn], acc[tm][tn], 0, 0, 0);
#pragma unroll
    for (int t2 = 0; t2 < 2; t2++)
#pragma unroll
      for (int tn2 = 0; tn2 < 2; tn2++)
        acc2[t2][tn2] = __builtin_amdgcn_mfma_f32_16x16x32_bf16(af2[t2], bp[tn2], acc2[t2][tn2], 0, 0, 0);
    __syncthreads();
  }
  // proj C-frags -> projF [128][32] fp32
#pragma unroll
  for (int t2 = 0; t2 < 2; t2++)
#pragma unroll
    for (int tn2 = 0; tn2 < 2; tn2++)
#pragma unroll
      for (int r = 0; r < 4; r++)
        projF[(w * 32 + t2 * 16 + quad * 4 + r) * 32 + tn2 * 16 + lrow] = acc2[t2][tn2][r];
  // stage RwT[n0..n0+128) -> Bt
  {
    uint4 vr0 = *(const uint4*)((const char*)RwT + (long)(n0 + (p0 >> 6)) * 64 + (p0 & 63));
    uint4 vr1 = *(const uint4*)((const char*)RwT + (long)(n0 + (p1 >> 6)) * 64 + (p1 & 63));
    *(uint4*)((char*)Bt + p0) = vr0;
    *(uint4*)((char*)Bt + p1) = vr1;
  }
  __syncthreads();
  // per-token 32 coefficients
  if (tid < 128) {
    float pr[32];
#pragma unroll
    for (int j = 0; j < 32; j++) pr[j] = projF[tid * 32 + j];
    float wo[32];
#pragma unroll
    for (int k = 0; k < 8; k++) { wo[k] = gl[k] * pr[8 + k]; wo[8 + k] = -gl[k] * pr[k]; }
#pragma unroll
    for (int kp = 0; kp < 8; kp++) {
      float sv = pr[16 + kp], tv = pr[24 + kp];
#pragma unroll
      for (int k = 0; k < 8; k++) {
        float gpb = gl[k] * pr[8 + k], gpa = gl[k] * pr[k];
        sv += gpb * Ml[k * 8 + kp]       - gpa * Ml[64 + k * 8 + kp];
        tv += gpb * Ml[128 + k * 8 + kp] - gpa * Ml[192 + k * 8 + kp];
      }
      wo[16 + kp] = gl[8 + kp] * sv;
      wo[24 + kp] = gl[16 + kp] * tv;
    }
#pragma unroll
    for (int j = 0; j < 32; j++) wLds[tid * 32 + j] = f2bf(wo[j]);
  }
  __syncthreads();
  // final K-chunk: coeffs @ RwT
  {
    bf16x8 af[4], bq[4];
#pragma unroll
    for (int tm = 0; tm < 4; tm++)
      af[tm] = *(const bf16x8*)(wLds + (mw + tm * 16 + lrow) * 32 + quad * 8);
#pragma unroll
    for (int tn = 0; tn < 4; tn++)
      bq[tn] = *(const bf16x8*)(Bt + (nw + tn * 16 + lrow) * 32 + quad * 8);
#pragma unroll
    for (int tm = 0; tm < 4; tm++)
#pragma unroll
      for (int tn = 0; tn < 4; tn++)
        acc[tm][tn] = __builtin_amdgcn_mfma_f32_16x16x32_bf16(af[tm], bq[tn], acc[tm][tn], 0, 0, 0);
  }
  // epilogue: + bias, fp32 store
#pragma unroll
  for (int tn = 0; tn < 4; tn++) {
    const int col = n0 + nw + tn * 16 + lrow;
    const float bias = bb[col];
#pragma unroll
    for (int tm = 0; tm < 4; tm++)
#pragma unroll
      for (int r = 0; r < 4; r++) {
        long row = m0 + mw + tm * 16 + quad * 4 + r;
        out[row * DD + col] = acc[tm][tn][r] + bias;
      }
  }
}

// ---------------------------------------------------------------------------
extern "C" void kernel_launch(void* const* d_in, const int* in_sizes, int n_in,
                              void* d_out, int out_size, void* d_ws, size_t ws_size,
                              hipStream_t stream) {
  const float* x   = (const float*)d_in[0];
  const float* Wb  = (const float*)d_in[1];
  const float* bb  = (const float*)d_in[2];
  const float* lng = (const float*)d_in[3];
  const float* lnb = (const float*)d_in[4];
  const float* Wc1 = (const float*)d_in[5];
  const float* bc1 = (const float*)d_in[6];
  const float* Wc2 = (const float*)d_in[7];
  const float* bc2 = (const float*)d_in[8];
  const float* Wrg = (const float*)d_in[9];
  const float* brg = (const float*)d_in[10];
  const float* Wrc = (const float*)d_in[11];
  const float* brc = (const float*)d_in[12];
  const float* Wsg = (const float*)d_in[13];
  const float* bsg = (const float*)d_in[14];
  const float* Wlc = (const float*)d_in[15];
  const float* blc = (const float*)d_in[16];
  const float* Us  = (const float*)d_in[17];
  const float* Vs  = (const float*)d_in[18];
  const float* Ul  = (const float*)d_in[19];
  const float* Vl  = (const float*)d_in[20];
  const float* Ao  = (const float*)d_in[21];
  const float* Bo  = (const float*)d_in[22];

  char* ws = (char*)d_ws;
  float* pooled = (float*)(ws + 0);         //  4*1024 f32  [memset]
  float* AWBW   = (float*)(ws + 16384);     // 16*1024 f32  [memset]
  float* gates  = (float*)(ws + 81920);     //  4*32  f32
  float* Mbuf   = (float*)(ws + 82432);     //  256   f32
  u16*   RwT    = (u16*)  (ws + 83456);     // 1024*32 bf16 -> 148992
  u16*   Wt     = (u16*)  (ws + 148992);    // 1024*1024 bf16 (2 MB) -> 2246144
  u16*   xb     = (u16*)  (ws + 2246144);   // 16384*1024 bf16 (32 MB), mode A
  float* out    = (float*)d_out;

  const bool modeA = ws_size >= (size_t)2246144 + 33554432;

  hipMemsetAsync(d_ws, 0, 81920, stream);   // pooled + AWBW accumulators
  if (modeA)
    k0_convert<<<256, 256, 0, stream>>>((const float4*)x, (ushort4*)xb);
  k1_pre<<<356, 256, 0, stream>>>(x, Wb, Ao, Bo, Us, Ul, pooled, AWBW, Mbuf, Wt);
  k2_gates_pack<<<8, 256, 0, stream>>>(pooled, AWBW, Vs, Vl,
                                       lng, lnb, Wc1, bc1, Wc2, bc2,
                                       Wrg, brg, Wrc, brc, Wsg, bsg, Wlc, blc,
                                       gates, RwT);
  if (modeA)
    k3_fused<true><<<1024, 256, 0, stream>>>(x, xb, Wt, Ao, Bo, Us, Ul,
                                             gates, Mbuf, RwT, bb, out);
  else
    k3_fused<false><<<1024, 256, 0, stream>>>(x, xb, Wt, Ao, Bo, Us, Ul,
                                              gates, Mbuf, RwT, bb, out);
}

// Round 6
// 354.643 us; speedup vs baseline: 1.6577x; 1.6577x over previous
//
#include <hip/hip_runtime.h>

typedef unsigned short u16;
typedef unsigned int   u32;
typedef __bf16 bf16x8 __attribute__((ext_vector_type(8)));
typedef float  f32x4  __attribute__((ext_vector_type(4)));

#define DD 1024

__device__ __forceinline__ u16 f2bf(float f) {
  u32 u = __float_as_uint(f);
  u32 r = (u + 0x7FFFu + ((u >> 16) & 1u)) >> 16;
  return (u16)r;
}

// ---------------------------------------------------------------------------
// k0f: fused x fp32 -> bf16 convert + pooled column sums. 256 blocks.
// block bid: rows [bid*64, bid*64+64), batch b = bid>>6. thread owns col4.
// ---------------------------------------------------------------------------
__global__ __launch_bounds__(256) void k0f_convert_pool(
    const float* __restrict__ x, u16* __restrict__ xb,
    float* __restrict__ pooled) {
  const int bid = blockIdx.x, tid = threadIdx.x;
  const int b = bid >> 6;
  const long r0 = (long)bid * 64;
  const int c0 = tid * 4;
  float s0 = 0.f, s1 = 0.f, s2 = 0.f, s3 = 0.f;
  for (int r = 0; r < 64; r++) {
    float4 v = *(const float4*)(x + (r0 + r) * DD + c0);
    ushort4 o;
    o.x = f2bf(v.x); o.y = f2bf(v.y); o.z = f2bf(v.z); o.w = f2bf(v.w);
    *(ushort4*)(xb + (r0 + r) * DD + c0) = o;
    s0 += v.x; s1 += v.y; s2 += v.z; s3 += v.w;
  }
  atomicAdd(&pooled[b * DD + c0 + 0], s0);
  atomicAdd(&pooled[b * DD + c0 + 1], s1);
  atomicAdd(&pooled[b * DD + c0 + 2], s2);
  atomicAdd(&pooled[b * DD + c0 + 3], s3);
}

// mode-B fallback: pooled only (no xb). 256 blocks.
__global__ __launch_bounds__(256) void k_pool(
    const float* __restrict__ x, float* __restrict__ pooled) {
  const int bid = blockIdx.x, tid = threadIdx.x;
  const int b = bid >> 6;
  const long r0 = (long)bid * 64;
  const int c0 = tid * 4;
  float s0 = 0.f, s1 = 0.f, s2 = 0.f, s3 = 0.f;
  for (int r = 0; r < 64; r++) {
    float4 v = *(const float4*)(x + (r0 + r) * DD + c0);
    s0 += v.x; s1 += v.y; s2 += v.z; s3 += v.w;
  }
  atomicAdd(&pooled[b * DD + c0 + 0], s0);
  atomicAdd(&pooled[b * DD + c0 + 1], s1);
  atomicAdd(&pooled[b * DD + c0 + 2], s2);
  atomicAdd(&pooled[b * DD + c0 + 3], s3);
}

// ---------------------------------------------------------------------------
// k1: blocks 0..31 : AWBW[16][1024] = {A,B}@W_base (fp32 atomics, split-i)
//     blocks 32..35: Mbuf: 4 Gram 8x8 (A.Us, B.Us, A.Ul, B.Ul)
//     blocks 36..39: Pb[32][1024] = bf16([Ao;Bo;Us;Ul])
//     blocks 40..295: Wt[n][k] = bf16(W[k][n])  (transpose + convert)
// ---------------------------------------------------------------------------
__global__ __launch_bounds__(256) void k1_pre(
    const float* __restrict__ W,
    const float* __restrict__ Ao, const float* __restrict__ Bo,
    const float* __restrict__ Us, const float* __restrict__ Ul,
    float* __restrict__ AWBW, float* __restrict__ Mbuf,
    u16* __restrict__ Pb, u16* __restrict__ Wt) {
  const int bid = blockIdx.x, tid = threadIdx.x;
  if (bid < 32) {
    __shared__ float red2[2][128][16];
    const int m = bid;
    const int n = (m & 7) * 128 + (tid & 127), q = m >> 3, ih = tid >> 7;
    float acc[16];
#pragma unroll
    for (int k = 0; k < 16; k++) acc[k] = 0.f;
    const int ib = q * 256 + ih * 128;
    for (int i = ib; i < ib + 128; i++) {
      float wv = W[(long)i * DD + n];
#pragma unroll
      for (int k = 0; k < 8; k++) {
        acc[k]     += Ao[k * DD + i] * wv;
        acc[k + 8] += Bo[k * DD + i] * wv;
      }
    }
#pragma unroll
    for (int k = 0; k < 16; k++) red2[ih][tid & 127][k] = acc[k];
    __syncthreads();
    if (ih == 0)
#pragma unroll
      for (int k = 0; k < 16; k++)
        atomicAdd(&AWBW[k * DD + n], red2[0][tid][k] + red2[1][tid][k]);
  } else if (bid < 36) {
    __shared__ float red[64][4];
    const int m = bid - 32;
    const float* L  = (m == 0 || m == 2) ? Ao : Bo;
    const float* Rr = (m < 2) ? Us : Ul;
    const int o = tid >> 2, ch = tid & 3;
    const int k = o >> 3, kp = o & 7;
    float a = 0.f;
    for (int i = ch * 256; i < ch * 256 + 256; i++)
      a += L[(long)k * DD + i] * Rr[(long)kp * DD + i];
    red[o][ch] = a;
    __syncthreads();
    if (tid < 64) Mbuf[m * 64 + tid] = red[tid][0] + red[tid][1] + red[tid][2] + red[tid][3];
  } else if (bid < 40) {
    const int m = bid - 36;
    const float* src = m == 0 ? Ao : m == 1 ? Bo : m == 2 ? Us : Ul;
#pragma unroll
    for (int j = 0; j < 8; j++)
      for (int q = 0; q < 4; q++) {
        int i = q * 256 + tid;
        Pb[(m * 8 + j) * DD + i] = f2bf(src[j * DD + i]);
      }
  } else {
    __shared__ u16 T[64][66];
    const int t = bid - 40, tr = t >> 4, tc = t & 15;
#pragma unroll
    for (int q2 = 0; q2 < 16; q2++) {
      int idx = q2 * 256 + tid, r = idx >> 6, c = idx & 63;
      T[r][c] = f2bf(W[(long)(tr * 64 + r) * DD + tc * 64 + c]);
    }
    __syncthreads();
#pragma unroll
    for (int q2 = 0; q2 < 16; q2++) {
      int idx = q2 * 256 + tid, c = idx >> 6, r = idx & 63;
      Wt[(long)(tc * 64 + c) * DD + tr * 64 + r] = T[r][c];
    }
  }
}

// ---------------------------------------------------------------------------
// k2a: h1pre[b][j] partial = sum_{d in chunk} z[d] * Wc1[d][j].
// grid = 32 (b = bid>>3, chunk = bid&7). Wc1 chunk staged in LDS (64 KB).
// ---------------------------------------------------------------------------
__global__ __launch_bounds__(256) void k2a_h1(
    const float* __restrict__ pooledsum,
    const float* __restrict__ lng, const float* __restrict__ lnb,
    const float* __restrict__ Wc1, float* __restrict__ h1pre) {
  __shared__ float zs[1024];
  __shared__ float wsh[16384];
  __shared__ float red[256];
  const int tid = threadIdx.x;
  const int b = blockIdx.x >> 3, ch = blockIdx.x & 7;
  // LN (redundant per block, cheap): thread owns 4 consecutive cols
  float4 v = *(const float4*)(pooledsum + b * DD + tid * 4);
  v.x *= (1.f / 4096.f); v.y *= (1.f / 4096.f); v.z *= (1.f / 4096.f); v.w *= (1.f / 4096.f);
  float s = v.x + v.y + v.z + v.w;
  float sq = v.x * v.x + v.y * v.y + v.z * v.z + v.w * v.w;
  red[tid] = s; __syncthreads();
  for (int st = 128; st > 0; st >>= 1) { if (tid < st) red[tid] += red[tid + st]; __syncthreads(); }
  float mu = red[0] * (1.f / 1024.f);
  __syncthreads();
  red[tid] = sq; __syncthreads();
  for (int st = 128; st > 0; st >>= 1) { if (tid < st) red[tid] += red[tid + st]; __syncthreads(); }
  float var = red[0] * (1.f / 1024.f) - mu * mu;
  float rs = rsqrtf(var + 1e-5f);
  __syncthreads();
  {
    float4 g = *(const float4*)(lng + tid * 4);
    float4 be = *(const float4*)(lnb + tid * 4);
    zs[tid * 4 + 0] = (v.x - mu) * rs * g.x + be.x;
    zs[tid * 4 + 1] = (v.y - mu) * rs * g.y + be.y;
    zs[tid * 4 + 2] = (v.z - mu) * rs * g.z + be.z;
    zs[tid * 4 + 3] = (v.w - mu) * rs * g.w + be.w;
  }
  // stage Wc1 chunk: rows [ch*128, ch*128+128) x 128 cols = 16384 f32
  {
    const float4* src = (const float4*)(Wc1 + ch * 16384);
    float4* dst = (float4*)wsh;
#pragma unroll
    for (int it = 0; it < 16; it++) dst[it * 256 + tid] = src[it * 256 + tid];
  }
  __syncthreads();
  const int j = tid & 127, half = tid >> 7;
  float a = 0.f;
#pragma unroll 8
  for (int dd = 0; dd < 64; dd++) {
    int ldi = half * 64 + dd;
    a += zs[ch * 128 + ldi] * wsh[ldi * 128 + j];
  }
  red[tid] = a;
  __syncthreads();
  if (tid < 128) atomicAdd(&h1pre[b * 128 + tid], red[tid] + red[tid + 128]);
}

// ---------------------------------------------------------------------------
// k2b: blocks 0..3: gelu(h1pre+bc1) @ Wc2 + bc2 -> heads -> gates[b][24]
//      blocks 4..7: pack RwT[n][32] = bf16{AW(8) BW(8) Vs(8) Vl(8)}(., n)
// ---------------------------------------------------------------------------
__global__ __launch_bounds__(256) void k2b_gates_pack(
    const float* __restrict__ h1pre, const float* __restrict__ AWBW,
    const float* Vs, const float* Vl,
    const float* bc1, const float* Wc2, const float* bc2,
    const float* Wrg, const float* brg, const float* Wrc, const float* brc,
    const float* Wsg, const float* bsg, const float* Wlc, const float* blc,
    float* __restrict__ gates, u16* __restrict__ RwT) {
  const int tid = threadIdx.x;
  if (blockIdx.x < 4) {
    __shared__ float wc2sh[16384];
    __shared__ float h1s[128], hb[128];
    __shared__ float red[256];
    __shared__ float hw[3200];
    const int b = blockIdx.x;
    // stage Wc2 (64 KB) + head weights (12.8 KB) coalesced
    {
      const float4* src = (const float4*)Wc2;
      float4* dst = (float4*)wc2sh;
#pragma unroll
      for (int it = 0; it < 16; it++) dst[it * 256 + tid] = src[it * 256 + tid];
    }
    for (int idx = tid; idx < 3200; idx += 256) {
      float vv;
      if (idx < 128)       vv = Wrg[idx];
      else if (idx < 1152) vv = Wrc[idx - 128];
      else if (idx < 2176) vv = Wsg[idx - 1152];
      else                 vv = Wlc[idx - 2176];
      hw[idx] = vv;
    }
    if (tid < 128) {
      float hv = h1pre[b * 128 + tid] + bc1[tid];
      float th = tanhf(0.7978845608028654f * (hv + 0.044715f * hv * hv * hv));
      h1s[tid] = 0.5f * hv * (1.f + th);
    }
    __syncthreads();
    const int i = tid & 127, half = tid >> 7;
    float a = 0.f;
#pragma unroll 8
    for (int k = 0; k < 64; k++) {
      int kk = half * 64 + k;
      a += h1s[kk] * wc2sh[kk * 128 + i];
    }
    red[tid] = a;
    __syncthreads();
    if (tid < 128) hb[tid] = red[tid] + red[tid + 128] + bc2[tid];
    __syncthreads();
    if (tid < 25) {
      float acc;
      if (tid == 0) {
        acc = brg[0];
        for (int k = 0; k < 128; k++) acc += hb[k] * hw[k];
        red[0] = 1.f / (1.f + expf(-acc));
      } else if (tid < 9) {
        int ci = tid - 1; acc = brc[ci];
        for (int k = 0; k < 128; k++) acc += hb[k] * hw[128 + k * 8 + ci];
        red[tid] = tanhf(acc);
      } else if (tid < 17) {
        int ci = tid - 9; acc = bsg[ci];
        for (int k = 0; k < 128; k++) acc += hb[k] * hw[1152 + k * 8 + ci];
        red[tid] = tanhf(acc);
      } else {
        int ci = tid - 17; acc = blc[ci];
        for (int k = 0; k < 128; k++) acc += hb[k] * hw[2176 + k * 8 + ci];
        red[tid] = tanhf(acc);
      }
    }
    __syncthreads();
    if (tid < 24) {
      float g = red[0];
      gates[b * 32 + tid] = (tid < 8) ? g * red[1 + tid] : red[1 + tid];
    }
  } else {
    const int n = (int)(blockIdx.x - 4) * 256 + tid;
#pragma unroll
    for (int j = 0; j < 8; j++) {
      RwT[n * 32 + j]      = f2bf(AWBW[j * DD + n]);
      RwT[n * 32 + 8 + j]  = f2bf(AWBW[(8 + j) * DD + n]);
      RwT[n * 32 + 16 + j] = f2bf(Vs[(long)j * DD + n]);
      RwT[n * 32 + 24 + j] = f2bf(Vl[(long)j * DD + n]);
    }
  }
}

// ---------------------------------------------------------------------------
// k3: fused GEMM. kc=0..31: out-acc += x@W (128x128), proj-acc += x@P^T.
//     Then in-block coefficients + final rank-32 K-chunk. Output fp32.
//     XB: A staged from pre-converted xb bf16; else from fp32 x w/ convert.
// ---------------------------------------------------------------------------
template <bool XB>
__global__ __launch_bounds__(256) void k3_fused(
    const float* __restrict__ xf, const u16* __restrict__ xb,
    const u16* __restrict__ Wt, const u16* __restrict__ Pb,
    const float* __restrict__ gates, const float* __restrict__ Mbuf,
    const u16* __restrict__ RwT, const float* __restrict__ bb,
    float* __restrict__ out) {
  __shared__ __align__(16) u16 At[4096];
  __shared__ __align__(16) u16 Bt[4096];
  __shared__ __align__(16) u16 Pt[1024];
  __shared__ float projF[128 * 32];
  __shared__ __align__(16) u16 wLds[4096];
  __shared__ float Ml[256];
  __shared__ float gl[24];
  const int tid = threadIdx.x, lane = tid & 63, w = tid >> 6;
  const int quad = lane >> 4, lrow = lane & 15;
  const int bn = blockIdx.x & 7, bm = blockIdx.x >> 3;
  const long m0 = (long)bm * 128;
  const int n0 = bn * 128;
  const int batch = bm >> 5;
  Ml[tid] = Mbuf[tid];
  if (tid < 24) gl[tid] = gates[batch * 32 + tid];
  const int mw = (w & 1) * 64, nw = (w >> 1) * 64;
  const int p0 = (w * 2) * 1024 + lane * 16, p1 = p0 + 1024;   // byte offsets
  f32x4 acc[4][4] = {};
  f32x4 acc2[2][2] = {};
  for (int kc = 0; kc < 32; kc++) {
    uint4 vb0 = *(const uint4*)((const char*)Wt + (long)(n0 + (p0 >> 6)) * 2048 + kc * 64 + (p0 & 63));
    uint4 vb1 = *(const uint4*)((const char*)Wt + (long)(n0 + (p1 >> 6)) * 2048 + kc * 64 + (p1 & 63));
    uint4 vp;
    if (tid < 128)
      vp = *(const uint4*)((const char*)Pb + (tid >> 2) * 2048 + kc * 64 + (tid & 3) * 16);
    if (XB) {
      uint4 va0 = *(const uint4*)((const char*)xb + (m0 + (p0 >> 6)) * 2048 + kc * 64 + (p0 & 63));
      uint4 va1 = *(const uint4*)((const char*)xb + (m0 + (p1 >> 6)) * 2048 + kc * 64 + (p1 & 63));
      *(uint4*)((char*)At + p0) = va0;
      *(uint4*)((char*)At + p1) = va1;
    } else {
      ushort4 oa[4];
#pragma unroll
      for (int i = 0; i < 4; i++) {
        int fi = i * 256 + tid, row = fi >> 3, c4 = (fi & 7) * 4;
        float4 v = *(const float4*)(xf + (m0 + row) * DD + kc * 32 + c4);
        oa[i].x = f2bf(v.x); oa[i].y = f2bf(v.y); oa[i].z = f2bf(v.z); oa[i].w = f2bf(v.w);
      }
#pragma unroll
      for (int i = 0; i < 4; i++) {
        int fi = i * 256 + tid, row = fi >> 3, c4 = (fi & 7) * 4;
        *(ushort4*)(At + row * 32 + c4) = oa[i];
      }
    }
    *(uint4*)((char*)Bt + p0) = vb0;
    *(uint4*)((char*)Bt + p1) = vb1;
    if (tid < 128) *(uint4*)((char*)Pt + (tid >> 2) * 64 + (tid & 3) * 16) = vp;
    __syncthreads();
    bf16x8 af[4], bq[4], af2[2], bp[2];
#pragma unroll
    for (int tm = 0; tm < 4; tm++)
      af[tm] = *(const bf16x8*)(At + (mw + tm * 16 + lrow) * 32 + quad * 8);
#pragma unroll
    for (int tn = 0; tn < 4; tn++)
      bq[tn] = *(const bf16x8*)(Bt + (nw + tn * 16 + lrow) * 32 + quad * 8);
#pragma unroll
    for (int t2 = 0; t2 < 2; t2++)
      af2[t2] = *(const bf16x8*)(At + (w * 32 + t2 * 16 + lrow) * 32 + quad * 8);
#pragma unroll
    for (int tn2 = 0; tn2 < 2; tn2++)
      bp[tn2] = *(const bf16x8*)(Pt + (tn2 * 16 + lrow) * 32 + quad * 8);
#pragma unroll
    for (int tm = 0; tm < 4; tm++)
#pragma unroll
      for (int tn = 0; tn < 4; tn++)
        acc[tm][tn] = __builtin_amdgcn_mfma_f32_16x16x32_bf16(af[tm], bq[tn], acc[tm][tn], 0, 0, 0);
#pragma unroll
    for (int t2 = 0; t2 < 2; t2++)
#pragma unroll
      for (int tn2 = 0; tn2 < 2; tn2++)
        acc2[t2][tn2] = __builtin_amdgcn_mfma_f32_16x16x32_bf16(af2[t2], bp[tn2], acc2[t2][tn2], 0, 0, 0);
    __syncthreads();
  }
  // proj C-frags -> projF [128][32] fp32
#pragma unroll
  for (int t2 = 0; t2 < 2; t2++)
#pragma unroll
    for (int tn2 = 0; tn2 < 2; tn2++)
#pragma unroll
      for (int r = 0; r < 4; r++)
        projF[(w * 32 + t2 * 16 + quad * 4 + r) * 32 + tn2 * 16 + lrow] = acc2[t2][tn2][r];
  // stage RwT[n0..n0+128) -> Bt
  {
    uint4 vr0 = *(const uint4*)((const char*)RwT + (long)(n0 + (p0 >> 6)) * 64 + (p0 & 63));
    uint4 vr1 = *(const uint4*)((const char*)RwT + (long)(n0 + (p1 >> 6)) * 64 + (p1 & 63));
    *(uint4*)((char*)Bt + p0) = vr0;
    *(uint4*)((char*)Bt + p1) = vr1;
  }
  __syncthreads();
  // per-token 32 coefficients
  if (tid < 128) {
    float pr[32];
#pragma unroll
    for (int j = 0; j < 32; j++) pr[j] = projF[tid * 32 + j];
    float wo[32];
#pragma unroll
    for (int k = 0; k < 8; k++) { wo[k] = gl[k] * pr[8 + k]; wo[8 + k] = -gl[k] * pr[k]; }
#pragma unroll
    for (int kp = 0; kp < 8; kp++) {
      float sv = pr[16 + kp], tv = pr[24 + kp];
#pragma unroll
      for (int k = 0; k < 8; k++) {
        float gpb = gl[k] * pr[8 + k], gpa = gl[k] * pr[k];
        sv += gpb * Ml[k * 8 + kp]       - gpa * Ml[64 + k * 8 + kp];
        tv += gpb * Ml[128 + k * 8 + kp] - gpa * Ml[192 + k * 8 + kp];
      }
      wo[16 + kp] = gl[8 + kp] * sv;
      wo[24 + kp] = gl[16 + kp] * tv;
    }
#pragma unroll
    for (int j = 0; j < 32; j++) wLds[tid * 32 + j] = f2bf(wo[j]);
  }
  __syncthreads();
  // final K-chunk: coeffs @ RwT
  {
    bf16x8 af[4], bq[4];
#pragma unroll
    for (int tm = 0; tm < 4; tm++)
      af[tm] = *(const bf16x8*)(wLds + (mw + tm * 16 + lrow) * 32 + quad * 8);
#pragma unroll
    for (int tn = 0; tn < 4; tn++)
      bq[tn] = *(const bf16x8*)(Bt + (nw + tn * 16 + lrow) * 32 + quad * 8);
#pragma unroll
    for (int tm = 0; tm < 4; tm++)
#pragma unroll
      for (int tn = 0; tn < 4; tn++)
        acc[tm][tn] = __builtin_amdgcn_mfma_f32_16x16x32_bf16(af[tm], bq[tn], acc[tm][tn], 0, 0, 0);
  }
  // epilogue: + bias, fp32 store
#pragma unroll
  for (int tn = 0; tn < 4; tn++) {
    const int col = n0 + nw + tn * 16 + lrow;
    const float bias = bb[col];
#pragma unroll
    for (int tm = 0; tm < 4; tm++)
#pragma unroll
      for (int r = 0; r < 4; r++) {
        long row = m0 + mw + tm * 16 + quad * 4 + r;
        out[row * DD + col] = acc[tm][tn][r] + bias;
      }
  }
}

// ---------------------------------------------------------------------------
extern "C" void kernel_launch(void* const* d_in, const int* in_sizes, int n_in,
                              void* d_out, int out_size, void* d_ws, size_t ws_size,
                              hipStream_t stream) {
  const float* x   = (const float*)d_in[0];
  const float* Wb  = (const float*)d_in[1];
  const float* bb  = (const float*)d_in[2];
  const float* lng = (const float*)d_in[3];
  const float* lnb = (const float*)d_in[4];
  const float* Wc1 = (const float*)d_in[5];
  const float* bc1 = (const float*)d_in[6];
  const float* Wc2 = (const float*)d_in[7];
  const float* bc2 = (const float*)d_in[8];
  const float* Wrg = (const float*)d_in[9];
  const float* brg = (const float*)d_in[10];
  const float* Wrc = (const float*)d_in[11];
  const float* brc = (const float*)d_in[12];
  const float* Wsg = (const float*)d_in[13];
  const float* bsg = (const float*)d_in[14];
  const float* Wlc = (const float*)d_in[15];
  const float* blc = (const float*)d_in[16];
  const float* Us  = (const float*)d_in[17];
  const float* Vs  = (const float*)d_in[18];
  const float* Ul  = (const float*)d_in[19];
  const float* Vl  = (const float*)d_in[20];
  const float* Ao  = (const float*)d_in[21];
  const float* Bo  = (const float*)d_in[22];

  char* ws = (char*)d_ws;
  float* pooled = (float*)(ws + 0);         //  4*1024 f32  [memset]
  float* AWBW   = (float*)(ws + 16384);     // 16*1024 f32  [memset]
  float* h1pre  = (float*)(ws + 81920);     //  4*128 f32   [memset] -> 83968
  float* gates  = (float*)(ws + 83968);     //  4*32  f32   -> 84480
  float* Mbuf   = (float*)(ws + 84480);     //  256   f32   -> 85504
  u16*   RwT    = (u16*)  (ws + 85504);     // 1024*32 bf16 -> 151040
  u16*   Pb     = (u16*)  (ws + 151040);    // 32*1024 bf16 -> 216576
  u16*   Wt     = (u16*)  (ws + 216576);    // 1024*1024 bf16 (2 MB) -> 2313728
  u16*   xb     = (u16*)  (ws + 2313728);   // 16384*1024 bf16 (32 MB), mode A
  float* out    = (float*)d_out;

  const bool modeA = ws_size >= (size_t)2313728 + 33554432;

  hipMemsetAsync(d_ws, 0, 83968, stream);   // pooled + AWBW + h1pre
  if (modeA)
    k0f_convert_pool<<<256, 256, 0, stream>>>(x, xb, pooled);
  else
    k_pool<<<256, 256, 0, stream>>>(x, pooled);
  k1_pre<<<296, 256, 0, stream>>>(Wb, Ao, Bo, Us, Ul, AWBW, Mbuf, Pb, Wt);
  k2a_h1<<<32, 256, 0, stream>>>(pooled, lng, lnb, Wc1, h1pre);
  k2b_gates_pack<<<8, 256, 0, stream>>>(h1pre, AWBW, Vs, Vl,
                                        bc1, Wc2, bc2, Wrg, brg, Wrc, brc,
                                        Wsg, bsg, Wlc, blc, gates, RwT);
  if (modeA)
    k3_fused<true><<<1024, 256, 0, stream>>>(x, xb, Wt, Pb, gates, Mbuf, RwT, bb, out);
  else
    k3_fused<false><<<1024, 256, 0, stream>>>(x, xb, Wt, Pb, gates, Mbuf, RwT, bb, out);
}